// Round 2
// baseline (338.990 us; speedup 1.0000x reference)
//
#include <hip/hip_runtime.h>
#include <hip/hip_bf16.h>

#define DMODEL 512
#define LEN 2048
#define NBATCH 4
#define TOPK 7          // k = int(log(2048)) = 7
#define LDK 40          // padded LDS stride (bf16 elems): 80B rows keep 16B alignment

typedef __attribute__((ext_vector_type(8))) short short8;
typedef __attribute__((ext_vector_type(4))) float floatx4;

__device__ __forceinline__ float b2f(ushort h) {
  union { uint u; float f; } c; c.u = ((uint)h) << 16; return c.f;
}
__device__ __forceinline__ ushort f2b(float f) {
  union { float f; uint u; } c; c.f = f;
  uint u = c.u;
  uint r = (u + 0x7fffu + ((u >> 16) & 1u)) >> 16;   // RNE
  return (ushort)r;
}

// dtype-flag load helpers: bf==1 -> buffer is packed bf16; bf==0 -> fp32
__device__ __forceinline__ float ld1(const void* p, size_t i, int bf) {
  return bf ? b2f(((const ushort*)p)[i]) : ((const float*)p)[i];
}
__device__ __forceinline__ void ld4v(const void* p, size_t i, int bf, float* o) {
  if (bf) {
    uint2 v = *(const uint2*)((const ushort*)p + i);
    const ushort* s = (const ushort*)&v;
#pragma unroll
    for (int j = 0; j < 4; ++j) o[j] = b2f(s[j]);
  } else {
    float4 a = *(const float4*)((const float*)p + i);
    o[0] = a.x; o[1] = a.y; o[2] = a.z; o[3] = a.w;
  }
}
__device__ __forceinline__ void ld8v(const void* p, size_t i, int bf, float* o) {
  if (bf) {
    uint4 v = *(const uint4*)((const ushort*)p + i);
    const ushort* s = (const ushort*)&v;
#pragma unroll
    for (int j = 0; j < 8; ++j) o[j] = b2f(s[j]);
  } else {
    float4 a = *(const float4*)((const float*)p + i);
    float4 b = *(const float4*)((const float*)p + i + 4);
    o[0] = a.x; o[1] = a.y; o[2] = a.z; o[3] = a.w;
    o[4] = b.x; o[5] = b.y; o[6] = b.z; o[7] = b.w;
  }
}

// ---------------- K0: detect input dtype from wq ----------------
// For each 32-bit word, the LOW ushort: if buffers are packed bf16, it is a
// bf16 weight ~0.02*N(0,1) -> exponent field in [~110,125]. If fp32, it is
// low mantissa bits -> exponent field uniform in 0..255. Count outliers.
__global__ void detect_dtype(const uint* __restrict__ probe, int* __restrict__ flag) {
  __shared__ int cnt[512];
  int t = threadIdx.x;
  uint u = probe[t];
  uint e = (u >> 7) & 0xFFu;
  cnt[t] = (e < 90u || e > 140u) ? 1 : 0;
  __syncthreads();
  for (int s = 256; s > 0; s >>= 1) {
    if (t < s) cnt[t] += cnt[t + s];
    __syncthreads();
  }
  if (t == 0) *flag = (cnt[0] < 50) ? 1 : 0;   // 1 = bf16, 0 = fp32
}

// ---------------- K1: partial column-sums of queries over L ----------------
__global__ void qsum_part(const void* __restrict__ q, float* __restrict__ P,
                          const int* __restrict__ flag) {
  int bf = *flag;
  int b = blockIdx.x >> 4, c = blockIdx.x & 15;
  int d = threadIdx.x;
  size_t base = (((size_t)b * LEN + (size_t)c * 128) << 9) + d;
  float acc = 0.f;
#pragma unroll 8
  for (int l = 0; l < 128; ++l) acc += ld1(q, base + ((size_t)l << 9), bf);
  P[(size_t)blockIdx.x * DMODEL + d] = acc;
}

// ---------------- K2: qsum -> qbar = qsum@wq -> u = wk@qbar ----------------
__global__ void small_chain(const float* __restrict__ P,
                            const void* __restrict__ wq,
                            const void* __restrict__ wk,
                            float* __restrict__ u,
                            const int* __restrict__ flag) {
  __shared__ float qs[DMODEL];
  __shared__ float qb[DMODEL];
  int bf = *flag;
  int b = blockIdx.x, t = threadIdx.x;
  float a = 0.f;
#pragma unroll
  for (int c = 0; c < 16; ++c) a += P[(size_t)(b * 16 + c) * DMODEL + t];
  qs[t] = a;
  __syncthreads();
  float acc = 0.f;
#pragma unroll 8
  for (int d = 0; d < DMODEL; ++d) acc += qs[d] * ld1(wq, (size_t)d * DMODEL + t, bf);
  qb[t] = acc;
  __syncthreads();
  float acc2 = 0.f;
#pragma unroll 8
  for (int dp = 0; dp < DMODEL; ++dp) acc2 += ld1(wk, (size_t)t * DMODEL + dp, bf) * qb[dp];
  u[(size_t)b * DMODEL + t] = acc2;
}

// ---------------- K3: mean_corr[b,j] = (keys[b,j,:] . u[b,:]) / (H*L) -------
__global__ void mean_corr_k(const void* __restrict__ keys,
                            const float* __restrict__ u,
                            float* __restrict__ mc,
                            const int* __restrict__ flag) {
  int bf = *flag;
  int wid = (blockIdx.x * 256 + threadIdx.x) >> 6;
  int lane = threadIdx.x & 63;
  int b = wid >> 11, j = wid & (LEN - 1);
  float kv[8];
  ld8v(keys, (((size_t)b * LEN + j) << 9) + lane * 8, bf, kv);
  const float* ub = u + (size_t)b * DMODEL + lane * 8;
  float acc = 0.f;
#pragma unroll
  for (int i = 0; i < 8; ++i) acc += kv[i] * ub[i];
#pragma unroll
  for (int off = 32; off > 0; off >>= 1) acc += __shfl_down(acc, off);
  if (lane == 0) mc[(size_t)b * LEN + j] = acc * (1.f / 16384.f);
}

// ---------------- K4: top-7 + softmax per batch ----------------
__global__ void topk_softmax(const float* __restrict__ mc,
                             float* __restrict__ wts, int* __restrict__ dls) {
  __shared__ float vals[LEN];
  __shared__ float rv[4];
  __shared__ int ri[4];
  __shared__ float bv_s[TOPK];
  __shared__ int bi_s[TOPK];
  int b = blockIdx.x, t = threadIdx.x;
  for (int i = t; i < LEN; i += 256) vals[i] = mc[(size_t)b * LEN + i];
  __syncthreads();
  for (int it = 0; it < TOPK; ++it) {
    float bv = -3.0e38f; int bi = 0;
#pragma unroll
    for (int c = 0; c < LEN / 256; ++c) {
      int i = t + c * 256;
      float v = vals[i];
      if (v > bv) { bv = v; bi = i; }
    }
#pragma unroll
    for (int off = 32; off > 0; off >>= 1) {
      float ov = __shfl_down(bv, off);
      int   oi = __shfl_down(bi, off);
      if (ov > bv || (ov == bv && oi < bi)) { bv = ov; bi = oi; }
    }
    if ((t & 63) == 0) { rv[t >> 6] = bv; ri[t >> 6] = bi; }
    __syncthreads();
    if (t == 0) {
      float fv = rv[0]; int fi = ri[0];
      for (int w = 1; w < 4; ++w)
        if (rv[w] > fv || (rv[w] == fv && ri[w] < fi)) { fv = rv[w]; fi = ri[w]; }
      bv_s[it] = fv; bi_s[it] = fi;
      vals[fi] = -3.0e38f;
    }
    __syncthreads();
  }
  if (t == 0) {
    float m = bv_s[0];
    float e[TOPK], s = 0.f;
#pragma unroll
    for (int i = 0; i < TOPK; ++i) { e[i] = __expf(bv_s[i] - m); s += e[i]; }
    float inv = 1.f / s;
#pragma unroll
    for (int i = 0; i < TOPK; ++i) {
      wts[b * 8 + i] = e[i] * inv;
      dls[b * 8 + i] = bi_s[i];
    }
  }
}

// ---------------- K5: W2[512,512](bf16) = wv @ wo (dtype-flagged inputs) ----
__global__ __launch_bounds__(256) void gemm_w2(
    const void* __restrict__ A, const void* __restrict__ B,
    ushort* __restrict__ C, const int* __restrict__ flag) {
  __shared__ ushort As[64 * LDK];
  __shared__ ushort Bs[64 * LDK];   // transposed: Bs[n][k]
  int bf = *flag;
  int t = threadIdx.x;
  int n0 = blockIdx.x * 64, m0 = blockIdx.y * 64;
  int w = t >> 6, lane = t & 63;
  int quad = lane >> 4, l16 = lane & 15;
  floatx4 acc[4] = {{0,0,0,0},{0,0,0,0},{0,0,0,0},{0,0,0,0}};
  int am = t >> 2, ak = (t & 3) * 8;
  int kp = t >> 4, nb = (t & 15) * 4;

  for (int k0 = 0; k0 < DMODEL; k0 += 32) {
    float a8[8];
    ld8v(A, (size_t)(m0 + am) * DMODEL + k0 + ak, bf, a8);
    union { ushort s[8]; uint4 v; } ap;
#pragma unroll
    for (int j = 0; j < 8; ++j) ap.s[j] = f2b(a8[j]);
    *(uint4*)(&As[am * LDK + ak]) = ap.v;

    float b0[4], b1[4];
    ld4v(B, (size_t)(k0 + 2 * kp) * DMODEL + n0 + nb, bf, b0);
    ld4v(B, (size_t)(k0 + 2 * kp + 1) * DMODEL + n0 + nb, bf, b1);
#pragma unroll
    for (int i = 0; i < 4; ++i) {
      ushort2 pr; pr.x = f2b(b0[i]); pr.y = f2b(b1[i]);
      *(ushort2*)(&Bs[(nb + i) * LDK + 2 * kp]) = pr;
    }
    __syncthreads();

    short8 af = *(const short8*)(&As[(w * 16 + l16) * LDK + quad * 8]);
#pragma unroll
    for (int c = 0; c < 4; ++c) {
      short8 bfr = *(const short8*)(&Bs[(c * 16 + l16) * LDK + quad * 8]);
      acc[c] = __builtin_amdgcn_mfma_f32_16x16x32_bf16(af, bfr, acc[c], 0, 0, 0);
    }
    __syncthreads();
  }
  int mrow = m0 + w * 16 + quad * 4;
#pragma unroll
  for (int c = 0; c < 4; ++c) {
    int col = n0 + c * 16 + l16;
#pragma unroll
    for (int r = 0; r < 4; ++r)
      C[(size_t)(mrow + r) * DMODEL + col] = f2b(acc[c][r]);
  }
}

// ---------------- K6: fused out = (sum_k w_k * values[(l+d_k)%L]) @ W2 ------
// tile M=32 x N=512, 256 threads = 4 waves; wave w: rows 16*(w&1), cols 256*(w>>1)
__global__ __launch_bounds__(256) void mixgemm(
    const void* __restrict__ values, const ushort* __restrict__ W2,
    const float* __restrict__ wts, const int* __restrict__ dls,
    void* __restrict__ out, const int* __restrict__ flag) {
  __shared__ ushort As[32 * LDK];
  __shared__ ushort Bs[512 * LDK];   // Bs[n][k]
  int bf = *flag;
  int t = threadIdx.x;
  int m0 = blockIdx.x * 32;
  int b = m0 >> 11, l0 = m0 & (LEN - 1);
  float w[TOPK]; int dl[TOPK];
#pragma unroll
  for (int i = 0; i < TOPK; ++i) { w[i] = wts[b * 8 + i]; dl[i] = dls[b * 8 + i]; }
  int wv = t >> 6, lane = t & 63;
  int quad = lane >> 4, l16 = lane & 15;
  int r0 = (wv & 1) * 16, c0 = (wv >> 1) * 256;
  floatx4 acc[16];
#pragma unroll
  for (int c = 0; c < 16; ++c) acc[c] = (floatx4){0, 0, 0, 0};
  int am = t >> 3, ak = (t & 7) * 4;   // A: 32 rows x 32 k, 4 elems/thread
  int kp = t >> 4, nb = (t & 15) * 4;  // B: 32 k x 64 n per pass, 8 passes

  for (int k0 = 0; k0 < DMODEL; k0 += 32) {
    // A tile: on-the-fly delay-mix of 7 rows
    float a4[4] = {0, 0, 0, 0};
#pragma unroll
    for (int i = 0; i < TOPK; ++i) {
      int src = (l0 + am + dl[i]) & (LEN - 1);
      size_t idx = (((size_t)b << 11) + src) * DMODEL + k0 + ak;
      float v[4]; ld4v(values, idx, bf, v);
#pragma unroll
      for (int j = 0; j < 4; ++j) a4[j] += w[i] * v[j];
    }
    ushort4 ap;
    ap.x = f2b(a4[0]); ap.y = f2b(a4[1]); ap.z = f2b(a4[2]); ap.w = f2b(a4[3]);
    *(ushort4*)(&As[am * LDK + ak]) = ap;
    // B tile: full 512-wide slab of W2 (always bf16)
#pragma unroll
    for (int nc = 0; nc < 8; ++nc) {
      int n = nc * 64 + nb;
      uint2 q0 = *(const uint2*)(W2 + (size_t)(k0 + 2 * kp) * DMODEL + n);
      uint2 q1 = *(const uint2*)(W2 + (size_t)(k0 + 2 * kp + 1) * DMODEL + n);
      const ushort* p0 = (const ushort*)&q0;
      const ushort* p1 = (const ushort*)&q1;
#pragma unroll
      for (int i2 = 0; i2 < 4; ++i2) {
        ushort2 pr; pr.x = p0[i2]; pr.y = p1[i2];
        *(ushort2*)(&Bs[(n + i2) * LDK + 2 * kp]) = pr;
      }
    }
    __syncthreads();
    short8 af = *(const short8*)(&As[(r0 + l16) * LDK + quad * 8]);
#pragma unroll
    for (int c = 0; c < 16; ++c) {
      short8 bfr = *(const short8*)(&Bs[(c0 + c * 16 + l16) * LDK + quad * 8]);
      acc[c] = __builtin_amdgcn_mfma_f32_16x16x32_bf16(af, bfr, acc[c], 0, 0, 0);
    }
    __syncthreads();
  }
  int mrow = m0 + r0 + quad * 4;
#pragma unroll
  for (int c = 0; c < 16; ++c) {
    int col = c0 + c * 16 + l16;
#pragma unroll
    for (int r = 0; r < 4; ++r) {
      size_t oidx = (size_t)(mrow + r) * DMODEL + col;
      float v = acc[c][r];
      if (bf) ((ushort*)out)[oidx] = f2b(v);
      else    ((float*)out)[oidx] = v;
    }
  }
}

extern "C" void kernel_launch(void* const* d_in, const int* in_sizes, int n_in,
                              void* d_out, int out_size, void* d_ws, size_t ws_size,
                              hipStream_t stream) {
  const void* queries = d_in[0];
  const void* keys    = d_in[1];
  const void* values  = d_in[2];
  const void* wq      = d_in[3];
  const void* wk      = d_in[4];
  const void* wv      = d_in[5];
  const void* wo      = d_in[6];

  char* ws = (char*)d_ws;
  float* P    = (float*)(ws + 0);            // 64*512*4   = 128 KB
  float* U    = (float*)(ws + 131072);       // 4*512*4    = 8 KB
  float* MC   = (float*)(ws + 139264);       // 4*2048*4   = 32 KB
  float* WT   = (float*)(ws + 172032);       // 4*8*4
  int*   DL   = (int*)  (ws + 172160);       // 4*8*4
  int*   FLAG = (int*)  (ws + 172288);       // 4 B (1 = bf16 inputs, 0 = fp32)
  ushort* W2  = (ushort*)(ws + 180224);      // 512*512*2  = 512 KB; total ~704 KB

  detect_dtype<<<1, 512, 0, stream>>>((const uint*)wq, FLAG);
  gemm_w2<<<dim3(8, 8), 256, 0, stream>>>(wv, wo, W2, FLAG);
  qsum_part<<<NBATCH * 16, 512, 0, stream>>>(queries, P, FLAG);
  small_chain<<<NBATCH, 512, 0, stream>>>(P, wq, wk, U, FLAG);
  mean_corr_k<<<NBATCH * LEN / 4, 256, 0, stream>>>(keys, U, MC, FLAG);
  topk_softmax<<<NBATCH, 256, 0, stream>>>(MC, WT, DL);
  mixgemm<<<NBATCH * LEN / 32, 256, 0, stream>>>(values, W2, WT, DL, d_out, FLAG);
}

// Round 3
// 190.899 us; speedup vs baseline: 1.7758x; 1.7758x over previous
//
#include <hip/hip_runtime.h>
#include <hip/hip_bf16.h>

#define DMODEL 512
#define LEN 2048
#define NBATCH 4
#define TOPK 7          // k = int(log(2048)) = 7
#define LDK 40          // padded LDS stride (bf16 elems): 80B rows keep 16B alignment

typedef __attribute__((ext_vector_type(8))) short short8;
typedef __attribute__((ext_vector_type(4))) float floatx4;

__device__ __forceinline__ float b2f(ushort h) {
  union { uint u; float f; } c; c.u = ((uint)h) << 16; return c.f;
}
__device__ __forceinline__ ushort f2b(float f) {
  union { float f; uint u; } c; c.f = f;
  uint u = c.u;
  uint r = (u + 0x7fffu + ((u >> 16) & 1u)) >> 16;   // RNE
  return (ushort)r;
}

// dtype-flag load helpers: bf==1 -> buffer is packed bf16; bf==0 -> fp32
__device__ __forceinline__ float ld1(const void* p, size_t i, int bf) {
  return bf ? b2f(((const ushort*)p)[i]) : ((const float*)p)[i];
}
__device__ __forceinline__ void ld4v(const void* p, size_t i, int bf, float* o) {
  if (bf) {
    uint2 v = *(const uint2*)((const ushort*)p + i);
    const ushort* s = (const ushort*)&v;
#pragma unroll
    for (int j = 0; j < 4; ++j) o[j] = b2f(s[j]);
  } else {
    float4 a = *(const float4*)((const float*)p + i);
    o[0] = a.x; o[1] = a.y; o[2] = a.z; o[3] = a.w;
  }
}
__device__ __forceinline__ void ld8v(const void* p, size_t i, int bf, float* o) {
  if (bf) {
    uint4 v = *(const uint4*)((const ushort*)p + i);
    const ushort* s = (const ushort*)&v;
#pragma unroll
    for (int j = 0; j < 8; ++j) o[j] = b2f(s[j]);
  } else {
    float4 a = *(const float4*)((const float*)p + i);
    float4 b = *(const float4*)((const float*)p + i + 4);
    o[0] = a.x; o[1] = a.y; o[2] = a.z; o[3] = a.w;
    o[4] = b.x; o[5] = b.y; o[6] = b.z; o[7] = b.w;
  }
}

// ---------------- K0: detect input dtype from wq ----------------
__global__ void detect_dtype(const uint* __restrict__ probe, int* __restrict__ flag) {
  __shared__ int cnt[512];
  int t = threadIdx.x;
  uint u = probe[t];
  uint e = (u >> 7) & 0xFFu;
  cnt[t] = (e < 90u || e > 140u) ? 1 : 0;
  __syncthreads();
  for (int s = 256; s > 0; s >>= 1) {
    if (t < s) cnt[t] += cnt[t + s];
    __syncthreads();
  }
  if (t == 0) *flag = (cnt[0] < 50) ? 1 : 0;   // 1 = bf16, 0 = fp32
}

// ---------------- K1: partial column-sums of queries over L ----------------
__global__ void qsum_part(const void* __restrict__ q, float* __restrict__ P,
                          const int* __restrict__ flag) {
  int bf = *flag;
  int b = blockIdx.x >> 4, c = blockIdx.x & 15;
  int d = threadIdx.x;
  size_t base = (((size_t)b * LEN + (size_t)c * 128) << 9) + d;
  float acc = 0.f;
#pragma unroll 8
  for (int l = 0; l < 128; ++l) acc += ld1(q, base + ((size_t)l << 9), bf);
  P[(size_t)blockIdx.x * DMODEL + d] = acc;
}

// ---------------- K2a: qb[b,j] = sum_d qs[b,d] * wq[d,j] ----------------
// grid = B*8 blocks of 256; block (b,g) computes j in [64g, 64g+64).
// 4 threads per output j, each covering 128 d-values; wq reads lane-coalesced.
__global__ void qbar_k(const float* __restrict__ P, const void* __restrict__ wq,
                       float* __restrict__ qb, const int* __restrict__ flag) {
  __shared__ float qs[DMODEL];
  __shared__ float red[4][64];
  int bf = *flag;
  int b = blockIdx.x >> 3, g = blockIdx.x & 7;
  int t = threadIdx.x;
  for (int d = t; d < DMODEL; d += 256) {
    float a = 0.f;
#pragma unroll
    for (int c = 0; c < 16; ++c) a += P[(size_t)(b * 16 + c) * DMODEL + d];
    qs[d] = a;
  }
  __syncthreads();
  int part = t >> 6, jl = t & 63;
  int j = g * 64 + jl;
  float acc = 0.f;
  int d0 = part * 128;
#pragma unroll 8
  for (int d = d0; d < d0 + 128; ++d)
    acc += qs[d] * ld1(wq, (size_t)d * DMODEL + j, bf);
  red[part][jl] = acc;
  __syncthreads();
  if (part == 0)
    qb[(size_t)b * DMODEL + j] = red[0][jl] + red[1][jl] + red[2][jl] + red[3][jl];
}

// ---------------- K2b: u[b,t] = wk[t,:] . qb[b,:] ----------------
// one wave per (b,t); grid = B*512/4 blocks of 256.
__global__ void u_k(const float* __restrict__ qb, const void* __restrict__ wk,
                    float* __restrict__ u, const int* __restrict__ flag) {
  int bf = *flag;
  int gw = (blockIdx.x * 256 + threadIdx.x) >> 6;
  int lane = threadIdx.x & 63;
  int b = gw >> 9, t = gw & 511;
  float kv[8];
  ld8v(wk, (size_t)t * DMODEL + lane * 8, bf, kv);
  const float* qbb = qb + (size_t)b * DMODEL + lane * 8;
  float acc = 0.f;
#pragma unroll
  for (int i = 0; i < 8; ++i) acc += kv[i] * qbb[i];
#pragma unroll
  for (int off = 32; off > 0; off >>= 1) acc += __shfl_down(acc, off);
  if (lane == 0) u[(size_t)b * DMODEL + t] = acc;
}

// ---------------- K3: mean_corr[b,j] = (keys[b,j,:] . u[b,:]) / (H*L) -------
__global__ void mean_corr_k(const void* __restrict__ keys,
                            const float* __restrict__ u,
                            float* __restrict__ mc,
                            const int* __restrict__ flag) {
  int bf = *flag;
  int wid = (blockIdx.x * 256 + threadIdx.x) >> 6;
  int lane = threadIdx.x & 63;
  int b = wid >> 11, j = wid & (LEN - 1);
  float kv[8];
  ld8v(keys, (((size_t)b * LEN + j) << 9) + lane * 8, bf, kv);
  const float* ub = u + (size_t)b * DMODEL + lane * 8;
  float acc = 0.f;
#pragma unroll
  for (int i = 0; i < 8; ++i) acc += kv[i] * ub[i];
#pragma unroll
  for (int off = 32; off > 0; off >>= 1) acc += __shfl_down(acc, off);
  if (lane == 0) mc[(size_t)b * LEN + j] = acc * (1.f / 16384.f);
}

// ---------------- K4: top-7 + softmax per batch ----------------
__global__ void topk_softmax(const float* __restrict__ mc,
                             float* __restrict__ wts, int* __restrict__ dls) {
  __shared__ float vals[LEN];
  __shared__ float rv[4];
  __shared__ int ri[4];
  __shared__ float bv_s[TOPK];
  __shared__ int bi_s[TOPK];
  int b = blockIdx.x, t = threadIdx.x;
  for (int i = t; i < LEN; i += 256) vals[i] = mc[(size_t)b * LEN + i];
  __syncthreads();
  for (int it = 0; it < TOPK; ++it) {
    float bv = -3.0e38f; int bi = 0;
#pragma unroll
    for (int c = 0; c < LEN / 256; ++c) {
      int i = t + c * 256;
      float v = vals[i];
      if (v > bv) { bv = v; bi = i; }
    }
#pragma unroll
    for (int off = 32; off > 0; off >>= 1) {
      float ov = __shfl_down(bv, off);
      int   oi = __shfl_down(bi, off);
      if (ov > bv || (ov == bv && oi < bi)) { bv = ov; bi = oi; }
    }
    if ((t & 63) == 0) { rv[t >> 6] = bv; ri[t >> 6] = bi; }
    __syncthreads();
    if (t == 0) {
      float fv = rv[0]; int fi = ri[0];
      for (int w = 1; w < 4; ++w)
        if (rv[w] > fv || (rv[w] == fv && ri[w] < fi)) { fv = rv[w]; fi = ri[w]; }
      bv_s[it] = fv; bi_s[it] = fi;
      vals[fi] = -3.0e38f;
    }
    __syncthreads();
  }
  if (t == 0) {
    float m = bv_s[0];
    float e[TOPK], s = 0.f;
#pragma unroll
    for (int i = 0; i < TOPK; ++i) { e[i] = __expf(bv_s[i] - m); s += e[i]; }
    float inv = 1.f / s;
#pragma unroll
    for (int i = 0; i < TOPK; ++i) {
      wts[b * 8 + i] = e[i] * inv;
      dls[b * 8 + i] = bi_s[i];
    }
  }
}

// ---------------- K5: W2[512,512](bf16) = wv @ wo (dtype-flagged inputs) ----
__global__ __launch_bounds__(256) void gemm_w2(
    const void* __restrict__ A, const void* __restrict__ B,
    ushort* __restrict__ C, const int* __restrict__ flag) {
  __shared__ ushort As[64 * LDK];
  __shared__ ushort Bs[64 * LDK];   // transposed: Bs[n][k]
  int bf = *flag;
  int t = threadIdx.x;
  int n0 = blockIdx.x * 64, m0 = blockIdx.y * 64;
  int w = t >> 6, lane = t & 63;
  int quad = lane >> 4, l16 = lane & 15;
  floatx4 acc[4] = {{0,0,0,0},{0,0,0,0},{0,0,0,0},{0,0,0,0}};
  int am = t >> 2, ak = (t & 3) * 8;
  int kp = t >> 4, nb = (t & 15) * 4;

  for (int k0 = 0; k0 < DMODEL; k0 += 32) {
    float a8[8];
    ld8v(A, (size_t)(m0 + am) * DMODEL + k0 + ak, bf, a8);
    union { ushort s[8]; uint4 v; } ap;
#pragma unroll
    for (int j = 0; j < 8; ++j) ap.s[j] = f2b(a8[j]);
    *(uint4*)(&As[am * LDK + ak]) = ap.v;

    float b0[4], b1[4];
    ld4v(B, (size_t)(k0 + 2 * kp) * DMODEL + n0 + nb, bf, b0);
    ld4v(B, (size_t)(k0 + 2 * kp + 1) * DMODEL + n0 + nb, bf, b1);
#pragma unroll
    for (int i = 0; i < 4; ++i) {
      ushort2 pr; pr.x = f2b(b0[i]); pr.y = f2b(b1[i]);
      *(ushort2*)(&Bs[(nb + i) * LDK + 2 * kp]) = pr;
    }
    __syncthreads();

    short8 af = *(const short8*)(&As[(w * 16 + l16) * LDK + quad * 8]);
#pragma unroll
    for (int c = 0; c < 4; ++c) {
      short8 bfr = *(const short8*)(&Bs[(c * 16 + l16) * LDK + quad * 8]);
      acc[c] = __builtin_amdgcn_mfma_f32_16x16x32_bf16(af, bfr, acc[c], 0, 0, 0);
    }
    __syncthreads();
  }
  int mrow = m0 + w * 16 + quad * 4;
#pragma unroll
  for (int c = 0; c < 4; ++c) {
    int col = n0 + c * 16 + l16;
#pragma unroll
    for (int r = 0; r < 4; ++r)
      C[(size_t)(mrow + r) * DMODEL + col] = f2b(acc[c][r]);
  }
}

// ---------------- K6: fused out = (sum_k w_k * values[(l+d_k)%L]) @ W2 ------
__global__ __launch_bounds__(256) void mixgemm(
    const void* __restrict__ values, const ushort* __restrict__ W2,
    const float* __restrict__ wts, const int* __restrict__ dls,
    void* __restrict__ out, const int* __restrict__ flag) {
  __shared__ ushort As[32 * LDK];
  __shared__ ushort Bs[512 * LDK];   // Bs[n][k]
  int bf = *flag;
  int t = threadIdx.x;
  int m0 = blockIdx.x * 32;
  int b = m0 >> 11, l0 = m0 & (LEN - 1);
  float w[TOPK]; int dl[TOPK];
#pragma unroll
  for (int i = 0; i < TOPK; ++i) { w[i] = wts[b * 8 + i]; dl[i] = dls[b * 8 + i]; }
  int wv = t >> 6, lane = t & 63;
  int quad = lane >> 4, l16 = lane & 15;
  int r0 = (wv & 1) * 16, c0 = (wv >> 1) * 256;
  floatx4 acc[16];
#pragma unroll
  for (int c = 0; c < 16; ++c) acc[c] = (floatx4){0, 0, 0, 0};
  int am = t >> 3, ak = (t & 7) * 4;   // A: 32 rows x 32 k, 4 elems/thread
  int kp = t >> 4, nb = (t & 15) * 4;  // B: 32 k x 64 n per pass, 8 passes

  for (int k0 = 0; k0 < DMODEL; k0 += 32) {
    float a4[4] = {0, 0, 0, 0};
#pragma unroll
    for (int i = 0; i < TOPK; ++i) {
      int src = (l0 + am + dl[i]) & (LEN - 1);
      size_t idx = (((size_t)b << 11) + src) * DMODEL + k0 + ak;
      float v[4]; ld4v(values, idx, bf, v);
#pragma unroll
      for (int j = 0; j < 4; ++j) a4[j] += w[i] * v[j];
    }
    ushort4 ap;
    ap.x = f2b(a4[0]); ap.y = f2b(a4[1]); ap.z = f2b(a4[2]); ap.w = f2b(a4[3]);
    *(ushort4*)(&As[am * LDK + ak]) = ap;
#pragma unroll
    for (int nc = 0; nc < 8; ++nc) {
      int n = nc * 64 + nb;
      uint2 q0 = *(const uint2*)(W2 + (size_t)(k0 + 2 * kp) * DMODEL + n);
      uint2 q1 = *(const uint2*)(W2 + (size_t)(k0 + 2 * kp + 1) * DMODEL + n);
      const ushort* p0 = (const ushort*)&q0;
      const ushort* p1 = (const ushort*)&q1;
#pragma unroll
      for (int i2 = 0; i2 < 4; ++i2) {
        ushort2 pr; pr.x = p0[i2]; pr.y = p1[i2];
        *(ushort2*)(&Bs[(n + i2) * LDK + 2 * kp]) = pr;
      }
    }
    __syncthreads();
    short8 af = *(const short8*)(&As[(r0 + l16) * LDK + quad * 8]);
#pragma unroll
    for (int c = 0; c < 16; ++c) {
      short8 bfr = *(const short8*)(&Bs[(c0 + c * 16 + l16) * LDK + quad * 8]);
      acc[c] = __builtin_amdgcn_mfma_f32_16x16x32_bf16(af, bfr, acc[c], 0, 0, 0);
    }
    __syncthreads();
  }
  int mrow = m0 + r0 + quad * 4;
#pragma unroll
  for (int c = 0; c < 16; ++c) {
    int col = c0 + c * 16 + l16;
#pragma unroll
    for (int r = 0; r < 4; ++r) {
      size_t oidx = (size_t)(mrow + r) * DMODEL + col;
      float v = acc[c][r];
      if (bf) ((ushort*)out)[oidx] = f2b(v);
      else    ((float*)out)[oidx] = v;
    }
  }
}

extern "C" void kernel_launch(void* const* d_in, const int* in_sizes, int n_in,
                              void* d_out, int out_size, void* d_ws, size_t ws_size,
                              hipStream_t stream) {
  const void* queries = d_in[0];
  const void* keys    = d_in[1];
  const void* values  = d_in[2];
  const void* wq      = d_in[3];
  const void* wk      = d_in[4];
  const void* wv      = d_in[5];
  const void* wo      = d_in[6];

  char* ws = (char*)d_ws;
  float* P    = (float*)(ws + 0);            // 64*512*4   = 128 KB
  float* U    = (float*)(ws + 131072);       // 4*512*4    = 8 KB
  float* MC   = (float*)(ws + 139264);       // 4*2048*4   = 32 KB
  float* WT   = (float*)(ws + 172032);       // 4*8*4
  int*   DL   = (int*)  (ws + 172160);       // 4*8*4
  int*   FLAG = (int*)  (ws + 172288);       // 4 B (1 = bf16 inputs, 0 = fp32)
  float* QB   = (float*)(ws + 172544);       // 4*512*4    = 8 KB
  ushort* W2  = (ushort*)(ws + 184320);      // 512*512*2  = 512 KB; total ~708 KB

  detect_dtype<<<1, 512, 0, stream>>>((const uint*)wq, FLAG);
  gemm_w2<<<dim3(8, 8), 256, 0, stream>>>(wv, wo, W2, FLAG);
  qsum_part<<<NBATCH * 16, 512, 0, stream>>>(queries, P, FLAG);
  qbar_k<<<NBATCH * 8, 256, 0, stream>>>(P, wq, QB, FLAG);
  u_k<<<NBATCH * 512 / 4, 256, 0, stream>>>(QB, wk, U, FLAG);
  mean_corr_k<<<NBATCH * LEN / 4, 256, 0, stream>>>(keys, U, MC, FLAG);
  topk_softmax<<<NBATCH, 256, 0, stream>>>(MC, WT, DL);
  mixgemm<<<NBATCH * LEN / 32, 256, 0, stream>>>(values, W2, WT, DL, d_out, FLAG);
}

// Round 4
// 177.878 us; speedup vs baseline: 1.9057x; 1.0732x over previous
//
#include <hip/hip_runtime.h>
#include <hip/hip_bf16.h>

#define DMODEL 512
#define LEN 2048
#define NBATCH 4
#define TOPK 7          // k = int(log(2048)) = 7
#define LDK 40          // padded LDS stride (bf16 elems): 80B rows keep 16B alignment

typedef __attribute__((ext_vector_type(8))) short short8;
typedef __attribute__((ext_vector_type(4))) float floatx4;

__device__ __forceinline__ float b2f(ushort h) {
  union { uint u; float f; } c; c.u = ((uint)h) << 16; return c.f;
}
__device__ __forceinline__ ushort f2b(float f) {
  union { float f; uint u; } c; c.f = f;
  uint u = c.u;
  uint r = (u + 0x7fffu + ((u >> 16) & 1u)) >> 16;   // RNE
  return (ushort)r;
}

// dtype-flag load helpers: bf==1 -> buffer is packed bf16; bf==0 -> fp32
__device__ __forceinline__ float ld1(const void* p, size_t i, int bf) {
  return bf ? b2f(((const ushort*)p)[i]) : ((const float*)p)[i];
}
__device__ __forceinline__ void ld4v(const void* p, size_t i, int bf, float* o) {
  if (bf) {
    uint2 v = *(const uint2*)((const ushort*)p + i);
    const ushort* s = (const ushort*)&v;
#pragma unroll
    for (int j = 0; j < 4; ++j) o[j] = b2f(s[j]);
  } else {
    float4 a = *(const float4*)((const float*)p + i);
    o[0] = a.x; o[1] = a.y; o[2] = a.z; o[3] = a.w;
  }
}
__device__ __forceinline__ void ld8v(const void* p, size_t i, int bf, float* o) {
  if (bf) {
    uint4 v = *(const uint4*)((const ushort*)p + i);
    const ushort* s = (const ushort*)&v;
#pragma unroll
    for (int j = 0; j < 8; ++j) o[j] = b2f(s[j]);
  } else {
    float4 a = *(const float4*)((const float*)p + i);
    float4 b = *(const float4*)((const float*)p + i + 4);
    o[0] = a.x; o[1] = a.y; o[2] = a.z; o[3] = a.w;
    o[4] = b.x; o[5] = b.y; o[6] = b.z; o[7] = b.w;
  }
}

// ---------------- K0: detect input dtype from wq ----------------
__global__ void detect_dtype(const uint* __restrict__ probe, int* __restrict__ flag) {
  __shared__ int cnt[512];
  int t = threadIdx.x;
  uint u = probe[t];
  uint e = (u >> 7) & 0xFFu;
  cnt[t] = (e < 90u || e > 140u) ? 1 : 0;
  __syncthreads();
  for (int s = 256; s > 0; s >>= 1) {
    if (t < s) cnt[t] += cnt[t + s];
    __syncthreads();
  }
  if (t == 0) *flag = (cnt[0] < 50) ? 1 : 0;   // 1 = bf16, 0 = fp32
}

// ---------------- K1: partial column-sums of queries over L ----------------
// grid = B*32 blocks of 512; block (b,c) sums rows [c*64, c*64+64).
__global__ void qsum_part(const void* __restrict__ q, float* __restrict__ P,
                          const int* __restrict__ flag) {
  int bf = *flag;
  int b = blockIdx.x >> 5, c = blockIdx.x & 31;
  int d = threadIdx.x;
  size_t base = (((size_t)b * LEN + (size_t)c * 64) << 9) + d;
  float acc = 0.f;
#pragma unroll 8
  for (int l = 0; l < 64; ++l) acc += ld1(q, base + ((size_t)l << 9), bf);
  P[(size_t)blockIdx.x * DMODEL + d] = acc;
}

// ---------------- K2a: qb[b,j] = sum_d qs[b,d] * wq[d,j] ----------------
__global__ void qbar_k(const float* __restrict__ P, const void* __restrict__ wq,
                       float* __restrict__ qb, const int* __restrict__ flag) {
  __shared__ float qs[DMODEL];
  __shared__ float red[4][64];
  int bf = *flag;
  int b = blockIdx.x >> 3, g = blockIdx.x & 7;
  int t = threadIdx.x;
  for (int d = t; d < DMODEL; d += 256) {
    float a = 0.f;
#pragma unroll
    for (int c = 0; c < 32; ++c) a += P[(size_t)(b * 32 + c) * DMODEL + d];
    qs[d] = a;
  }
  __syncthreads();
  int part = t >> 6, jl = t & 63;
  int j = g * 64 + jl;
  float acc = 0.f;
  int d0 = part * 128;
#pragma unroll 8
  for (int d = d0; d < d0 + 128; ++d)
    acc += qs[d] * ld1(wq, (size_t)d * DMODEL + j, bf);
  red[part][jl] = acc;
  __syncthreads();
  if (part == 0)
    qb[(size_t)b * DMODEL + j] = red[0][jl] + red[1][jl] + red[2][jl] + red[3][jl];
}

// ---------------- K2b: u[b,t] = wk[t,:] . qb[b,:] ----------------
__global__ void u_k(const float* __restrict__ qb, const void* __restrict__ wk,
                    float* __restrict__ u, const int* __restrict__ flag) {
  int bf = *flag;
  int gw = (blockIdx.x * 256 + threadIdx.x) >> 6;
  int lane = threadIdx.x & 63;
  int b = gw >> 9, t = gw & 511;
  float kv[8];
  ld8v(wk, (size_t)t * DMODEL + lane * 8, bf, kv);
  const float* qbb = qb + (size_t)b * DMODEL + lane * 8;
  float acc = 0.f;
#pragma unroll
  for (int i = 0; i < 8; ++i) acc += kv[i] * qbb[i];
#pragma unroll
  for (int off = 32; off > 0; off >>= 1) acc += __shfl_down(acc, off);
  if (lane == 0) u[(size_t)b * DMODEL + t] = acc;
}

// ---------------- K3: mean_corr[b,j] = (keys[b,j,:] . u[b,:]) / (H*L) -------
__global__ void mean_corr_k(const void* __restrict__ keys,
                            const float* __restrict__ u,
                            float* __restrict__ mc,
                            const int* __restrict__ flag) {
  int bf = *flag;
  int wid = (blockIdx.x * 256 + threadIdx.x) >> 6;
  int lane = threadIdx.x & 63;
  int b = wid >> 11, j = wid & (LEN - 1);
  float kv[8];
  ld8v(keys, (((size_t)b * LEN + j) << 9) + lane * 8, bf, kv);
  const float* ub = u + (size_t)b * DMODEL + lane * 8;
  float acc = 0.f;
#pragma unroll
  for (int i = 0; i < 8; ++i) acc += kv[i] * ub[i];
#pragma unroll
  for (int off = 32; off > 0; off >>= 1) acc += __shfl_down(acc, off);
  if (lane == 0) mc[(size_t)b * LEN + j] = acc * (1.f / 16384.f);
}

// ---------------- K4: top-7 + softmax per batch ----------------
__global__ void topk_softmax(const float* __restrict__ mc,
                             float* __restrict__ wts, int* __restrict__ dls) {
  __shared__ float vals[LEN];
  __shared__ float rv[4];
  __shared__ int ri[4];
  __shared__ float bv_s[TOPK];
  __shared__ int bi_s[TOPK];
  int b = blockIdx.x, t = threadIdx.x;
  for (int i = t; i < LEN; i += 256) vals[i] = mc[(size_t)b * LEN + i];
  __syncthreads();
  for (int it = 0; it < TOPK; ++it) {
    float bv = -3.0e38f; int bi = 0;
#pragma unroll
    for (int c = 0; c < LEN / 256; ++c) {
      int i = t + c * 256;
      float v = vals[i];
      if (v > bv) { bv = v; bi = i; }
    }
#pragma unroll
    for (int off = 32; off > 0; off >>= 1) {
      float ov = __shfl_down(bv, off);
      int   oi = __shfl_down(bi, off);
      if (ov > bv || (ov == bv && oi < bi)) { bv = ov; bi = oi; }
    }
    if ((t & 63) == 0) { rv[t >> 6] = bv; ri[t >> 6] = bi; }
    __syncthreads();
    if (t == 0) {
      float fv = rv[0]; int fi = ri[0];
      for (int w = 1; w < 4; ++w)
        if (rv[w] > fv || (rv[w] == fv && ri[w] < fi)) { fv = rv[w]; fi = ri[w]; }
      bv_s[it] = fv; bi_s[it] = fi;
      vals[fi] = -3.0e38f;
    }
    __syncthreads();
  }
  if (t == 0) {
    float m = bv_s[0];
    float e[TOPK], s = 0.f;
#pragma unroll
    for (int i = 0; i < TOPK; ++i) { e[i] = __expf(bv_s[i] - m); s += e[i]; }
    float inv = 1.f / s;
#pragma unroll
    for (int i = 0; i < TOPK; ++i) {
      wts[b * 8 + i] = e[i] * inv;
      dls[b * 8 + i] = bi_s[i];
    }
  }
}

// ---------------- K5: W2T[n][m] = (wv @ wo)^T, bf16, LDS-transposed epilogue -
__global__ __launch_bounds__(256) void gemm_w2(
    const void* __restrict__ A, const void* __restrict__ B,
    ushort* __restrict__ W2T, const int* __restrict__ flag) {
  __shared__ ushort As[64 * LDK];
  __shared__ ushort Bs[64 * LDK];   // transposed: Bs[n][k]
  __shared__ ushort Ts[64 * 72];    // epilogue transpose tile (stride 72: 2-way max)
  int bf = *flag;
  int t = threadIdx.x;
  int n0 = blockIdx.x * 64, m0 = blockIdx.y * 64;
  int w = t >> 6, lane = t & 63;
  int quad = lane >> 4, l16 = lane & 15;
  floatx4 acc[4] = {{0,0,0,0},{0,0,0,0},{0,0,0,0},{0,0,0,0}};
  int am = t >> 2, ak = (t & 3) * 8;
  int kp = t >> 4, nb = (t & 15) * 4;

  for (int k0 = 0; k0 < DMODEL; k0 += 32) {
    float a8[8];
    ld8v(A, (size_t)(m0 + am) * DMODEL + k0 + ak, bf, a8);
    union { ushort s[8]; uint4 v; } ap;
#pragma unroll
    for (int j = 0; j < 8; ++j) ap.s[j] = f2b(a8[j]);
    *(uint4*)(&As[am * LDK + ak]) = ap.v;

    float b0[4], b1[4];
    ld4v(B, (size_t)(k0 + 2 * kp) * DMODEL + n0 + nb, bf, b0);
    ld4v(B, (size_t)(k0 + 2 * kp + 1) * DMODEL + n0 + nb, bf, b1);
#pragma unroll
    for (int i = 0; i < 4; ++i) {
      ushort2 pr; pr.x = f2b(b0[i]); pr.y = f2b(b1[i]);
      *(ushort2*)(&Bs[(nb + i) * LDK + 2 * kp]) = pr;
    }
    __syncthreads();

    short8 af = *(const short8*)(&As[(w * 16 + l16) * LDK + quad * 8]);
#pragma unroll
    for (int c = 0; c < 4; ++c) {
      short8 bfr = *(const short8*)(&Bs[(c * 16 + l16) * LDK + quad * 8]);
      acc[c] = __builtin_amdgcn_mfma_f32_16x16x32_bf16(af, bfr, acc[c], 0, 0, 0);
    }
    __syncthreads();
  }
  // transpose through LDS: Ts[col_local][row_local]
#pragma unroll
  for (int c = 0; c < 4; ++c) {
    int cl = c * 16 + l16;
#pragma unroll
    for (int r = 0; r < 4; ++r)
      Ts[cl * 72 + (w * 16 + quad * 4 + r)] = f2b(acc[c][r]);
  }
  __syncthreads();
  int nl = t >> 2, ch = t & 3;
  uint4 v0 = *(const uint4*)(&Ts[nl * 72 + ch * 16]);
  uint4 v1 = *(const uint4*)(&Ts[nl * 72 + ch * 16 + 8]);
  ushort* dst = W2T + (size_t)(n0 + nl) * DMODEL + m0 + ch * 16;
  *(uint4*)dst = v0;
  *(uint4*)(dst + 8) = v1;
}

// ---------------- K6a: Amix[row][d] = sum_k w_k * values[b,(l+d_k)%L,d] -----
__global__ void mix_k(const void* __restrict__ values,
                      const float* __restrict__ wts, const int* __restrict__ dls,
                      ushort* __restrict__ Amix, const int* __restrict__ flag) {
  int bf = *flag;
  int t = threadIdx.x;
  int row = blockIdx.x * 4 + (t >> 6);
  int lane = t & 63;
  int b = row >> 11, l = row & (LEN - 1);
  float w[TOPK]; int dl[TOPK];
#pragma unroll
  for (int i = 0; i < TOPK; ++i) { w[i] = wts[b * 8 + i]; dl[i] = dls[b * 8 + i]; }
  float acc[8] = {0,0,0,0,0,0,0,0};
#pragma unroll
  for (int i = 0; i < TOPK; ++i) {
    int src = (l + dl[i]) & (LEN - 1);
    float v[8];
    ld8v(values, (((size_t)b * LEN + src) << 9) + lane * 8, bf, v);
#pragma unroll
    for (int j = 0; j < 8; ++j) acc[j] += w[i] * v[j];
  }
  union { ushort o[8]; uint4 v; } pk;
#pragma unroll
  for (int j = 0; j < 8; ++j) pk.o[j] = f2b(acc[j]);
  *(uint4*)(Amix + ((size_t)row << 9) + lane * 8) = pk.v;
}

// ---------------- K6b: out[8192,512] = Amix[8192,512] @ W2T^T ----------------
// 128x128 tile, BK=32, 256 threads = 4 waves (2x2 wave grid, 64x64 each).
__global__ __launch_bounds__(256) void gemm_out(
    const ushort* __restrict__ Amix, const ushort* __restrict__ W2T,
    void* __restrict__ out, const int* __restrict__ flag) {
  __shared__ ushort As[128 * LDK];
  __shared__ ushort Bs[128 * LDK];
  int bf = *flag;
  int t = threadIdx.x;
  int n0 = blockIdx.x * 128, m0 = blockIdx.y * 128;
  int w = t >> 6, lane = t & 63;
  int quad = lane >> 4, l16 = lane & 15;
  int wr = (w & 1) * 64, wc = (w >> 1) * 64;
  floatx4 acc[4][4];
#pragma unroll
  for (int r = 0; r < 4; ++r)
#pragma unroll
    for (int c = 0; c < 4; ++c) acc[r][c] = (floatx4){0, 0, 0, 0};
  int sr = t >> 2, sc = (t & 3) * 8;

  for (int k0 = 0; k0 < DMODEL; k0 += 32) {
    *(uint4*)(&As[sr * LDK + sc])        = *(const uint4*)(Amix + (size_t)(m0 + sr) * DMODEL + k0 + sc);
    *(uint4*)(&As[(sr + 64) * LDK + sc]) = *(const uint4*)(Amix + (size_t)(m0 + sr + 64) * DMODEL + k0 + sc);
    *(uint4*)(&Bs[sr * LDK + sc])        = *(const uint4*)(W2T + (size_t)(n0 + sr) * DMODEL + k0 + sc);
    *(uint4*)(&Bs[(sr + 64) * LDK + sc]) = *(const uint4*)(W2T + (size_t)(n0 + sr + 64) * DMODEL + k0 + sc);
    __syncthreads();
    short8 af[4], bfg[4];
#pragma unroll
    for (int r = 0; r < 4; ++r)
      af[r] = *(const short8*)(&As[(wr + r * 16 + l16) * LDK + quad * 8]);
#pragma unroll
    for (int c = 0; c < 4; ++c)
      bfg[c] = *(const short8*)(&Bs[(wc + c * 16 + l16) * LDK + quad * 8]);
#pragma unroll
    for (int r = 0; r < 4; ++r)
#pragma unroll
      for (int c = 0; c < 4; ++c)
        acc[r][c] = __builtin_amdgcn_mfma_f32_16x16x32_bf16(af[r], bfg[c], acc[r][c], 0, 0, 0);
    __syncthreads();
  }
#pragma unroll
  for (int r = 0; r < 4; ++r) {
    int row = m0 + wr + r * 16 + quad * 4;
#pragma unroll
    for (int c = 0; c < 4; ++c) {
      int col = n0 + wc + c * 16 + l16;
#pragma unroll
      for (int rr = 0; rr < 4; ++rr) {
        size_t oidx = (size_t)(row + rr) * DMODEL + col;
        float v = acc[r][c][rr];
        if (bf) ((ushort*)out)[oidx] = f2b(v);
        else    ((float*)out)[oidx] = v;
      }
    }
  }
}

extern "C" void kernel_launch(void* const* d_in, const int* in_sizes, int n_in,
                              void* d_out, int out_size, void* d_ws, size_t ws_size,
                              hipStream_t stream) {
  const void* queries = d_in[0];
  const void* keys    = d_in[1];
  const void* values  = d_in[2];
  const void* wq      = d_in[3];
  const void* wk      = d_in[4];
  const void* wv      = d_in[5];
  const void* wo      = d_in[6];

  char* ws = (char*)d_ws;
  float* P     = (float*)(ws + 0);           // 128*512*4 = 256 KB
  ushort* W2T  = (ushort*)(ws + 262144);     // 512*512*2 = 512 KB
  float* QB    = (float*)(ws + 786432);      // 8 KB
  float* U     = (float*)(ws + 794624);      // 8 KB
  float* MC    = (float*)(ws + 802816);      // 32 KB
  float* WT    = (float*)(ws + 835584);      // 128 B
  int*   DL    = (int*)  (ws + 835712);      // 128 B
  int*   FLAG  = (int*)  (ws + 835840);      // 4 B
  ushort* AMIX = (ushort*)(ws + 1048576);    // 8192*512*2 = 8 MB; total 9 MB

  detect_dtype<<<1, 512, 0, stream>>>((const uint*)wq, FLAG);
  gemm_w2<<<dim3(8, 8), 256, 0, stream>>>(wv, wo, W2T, FLAG);
  qsum_part<<<NBATCH * 32, 512, 0, stream>>>(queries, P, FLAG);
  qbar_k<<<NBATCH * 8, 256, 0, stream>>>(P, wq, QB, FLAG);
  u_k<<<NBATCH * 512 / 4, 256, 0, stream>>>(QB, wk, U, FLAG);
  mean_corr_k<<<NBATCH * LEN / 4, 256, 0, stream>>>(keys, U, MC, FLAG);
  topk_softmax<<<NBATCH, 256, 0, stream>>>(MC, WT, DL);
  mix_k<<<NBATCH * LEN / 4, 256, 0, stream>>>(values, WT, DL, AMIX, FLAG);
  gemm_out<<<dim3(4, 64), 256, 0, stream>>>(AMIX, W2T, d_out, FLAG);
}

// Round 5
// 167.149 us; speedup vs baseline: 2.0281x; 1.0642x over previous
//
#include <hip/hip_runtime.h>
#include <hip/hip_bf16.h>

#define DMODEL 512
#define LEN 2048
#define NBATCH 4
#define TOPK 7          // k = int(log(2048)) = 7
#define LDK 40          // padded LDS stride (bf16 elems): 80B rows keep 16B alignment

typedef __attribute__((ext_vector_type(8))) short short8;
typedef __attribute__((ext_vector_type(4))) float floatx4;

__device__ __forceinline__ float b2f(ushort h) {
  union { uint u; float f; } c; c.u = ((uint)h) << 16; return c.f;
}
__device__ __forceinline__ ushort f2b(float f) {
  union { float f; uint u; } c; c.f = f;
  uint u = c.u;
  uint r = (u + 0x7fffu + ((u >> 16) & 1u)) >> 16;   // RNE
  return (ushort)r;
}

// dtype-flag load helpers: bf==1 -> buffer is packed bf16; bf==0 -> fp32
__device__ __forceinline__ float ld1(const void* p, size_t i, int bf) {
  return bf ? b2f(((const ushort*)p)[i]) : ((const float*)p)[i];
}
__device__ __forceinline__ void ld4v(const void* p, size_t i, int bf, float* o) {
  if (bf) {
    uint2 v = *(const uint2*)((const ushort*)p + i);
    const ushort* s = (const ushort*)&v;
#pragma unroll
    for (int j = 0; j < 4; ++j) o[j] = b2f(s[j]);
  } else {
    float4 a = *(const float4*)((const float*)p + i);
    o[0] = a.x; o[1] = a.y; o[2] = a.z; o[3] = a.w;
  }
}
__device__ __forceinline__ void ld8v(const void* p, size_t i, int bf, float* o) {
  if (bf) {
    uint4 v = *(const uint4*)((const ushort*)p + i);
    const ushort* s = (const ushort*)&v;
#pragma unroll
    for (int j = 0; j < 8; ++j) o[j] = b2f(s[j]);
  } else {
    float4 a = *(const float4*)((const float*)p + i);
    float4 b = *(const float4*)((const float*)p + i + 4);
    o[0] = a.x; o[1] = a.y; o[2] = a.z; o[3] = a.w;
    o[4] = b.x; o[5] = b.y; o[6] = b.z; o[7] = b.w;
  }
}

// per-block dtype self-detect from wq's first 512 words (L2-hot after block 0).
// bf16-packed -> low-ushort exponent concentrated in [90,140]; fp32 -> uniform.
__device__ __forceinline__ int detect_bf16(const void* probe) {
  __shared__ int s_flag;
  int t = threadIdx.x;
  if (t < 64) {
    const uint4* p = (const uint4*)probe;
    uint4 a = p[t * 2];
    uint4 b = p[t * 2 + 1];
    uint w[8] = {a.x, a.y, a.z, a.w, b.x, b.y, b.z, b.w};
    int c = 0;
#pragma unroll
    for (int j = 0; j < 8; ++j) {
      uint e = (w[j] >> 7) & 0xFFu;
      c += (e < 90u || e > 140u) ? 1 : 0;
    }
#pragma unroll
    for (int off = 32; off > 0; off >>= 1) c += __shfl_down(c, off);
    if (t == 0) s_flag = (c < 50) ? 1 : 0;   // 1 = bf16, 0 = fp32
  }
  __syncthreads();
  return s_flag;
}

// ---------------- K1 (fused): qsum partials | values->bf16 | W2T GEMM -------
// blocks [0,256): qsum   — block (b,c): sum 32 rows of queries, 512 d.
// blocks [256,2304): v2b — 4 rows each, fp32->bf16 (or copy) into VB.
// blocks [2304,2368): w2 — 64x64 MFMA tile of W2T = (wv@wo)^T.
__global__ __launch_bounds__(256) void prep_k(
    const void* __restrict__ queries, const void* __restrict__ values,
    const void* __restrict__ wv, const void* __restrict__ wo,
    const void* __restrict__ probe,
    float* __restrict__ P, ushort* __restrict__ VB, ushort* __restrict__ W2T) {
  __shared__ ushort As[64 * LDK];
  __shared__ ushort Bs[64 * LDK];
  __shared__ ushort Ts[64 * 72];
  int bf = detect_bf16(probe);
  int blk = blockIdx.x;
  int t = threadIdx.x;
  if (blk < 256) {
    int b = blk >> 6, c = blk & 63;
    size_t base = (((size_t)b * LEN + (size_t)c * 32) << 9) + t;
    float a0 = 0.f, a1 = 0.f;
#pragma unroll 8
    for (int l = 0; l < 32; ++l) {
      a0 += ld1(queries, base + ((size_t)l << 9), bf);
      a1 += ld1(queries, base + ((size_t)l << 9) + 256, bf);
    }
    P[(size_t)blk * DMODEL + t] = a0;
    P[(size_t)blk * DMODEL + t + 256] = a1;
  } else if (blk < 2304) {
    int r = (blk - 256) * 4 + (t >> 6);
    int lane = t & 63;
    float v[8];
    ld8v(values, ((size_t)r << 9) + lane * 8, bf, v);
    union { ushort o[8]; uint4 u; } pk;
#pragma unroll
    for (int j = 0; j < 8; ++j) pk.o[j] = f2b(v[j]);
    *(uint4*)(VB + ((size_t)r << 9) + lane * 8) = pk.u;
  } else {
    int wb = blk - 2304;
    int n0 = (wb & 7) * 64, m0 = (wb >> 3) * 64;
    int w = t >> 6, lane = t & 63;
    int quad = lane >> 4, l16 = lane & 15;
    floatx4 acc[4] = {{0,0,0,0},{0,0,0,0},{0,0,0,0},{0,0,0,0}};
    int am = t >> 2, ak = (t & 3) * 8;
    int kp = t >> 4, nb = (t & 15) * 4;
    for (int k0 = 0; k0 < DMODEL; k0 += 32) {
      float a8[8];
      ld8v(wv, (size_t)(m0 + am) * DMODEL + k0 + ak, bf, a8);
      union { ushort s[8]; uint4 v; } ap;
#pragma unroll
      for (int j = 0; j < 8; ++j) ap.s[j] = f2b(a8[j]);
      *(uint4*)(&As[am * LDK + ak]) = ap.v;
      float b0[4], b1[4];
      ld4v(wo, (size_t)(k0 + 2 * kp) * DMODEL + n0 + nb, bf, b0);
      ld4v(wo, (size_t)(k0 + 2 * kp + 1) * DMODEL + n0 + nb, bf, b1);
#pragma unroll
      for (int i = 0; i < 4; ++i) {
        ushort2 pr; pr.x = f2b(b0[i]); pr.y = f2b(b1[i]);
        *(ushort2*)(&Bs[(nb + i) * LDK + 2 * kp]) = pr;
      }
      __syncthreads();
      short8 af = *(const short8*)(&As[(w * 16 + l16) * LDK + quad * 8]);
#pragma unroll
      for (int c = 0; c < 4; ++c) {
        short8 bfr = *(const short8*)(&Bs[(c * 16 + l16) * LDK + quad * 8]);
        acc[c] = __builtin_amdgcn_mfma_f32_16x16x32_bf16(af, bfr, acc[c], 0, 0, 0);
      }
      __syncthreads();
    }
    // transposed epilogue through LDS (stride 72 => worst 2-way = free)
#pragma unroll
    for (int c = 0; c < 4; ++c) {
      int cl = c * 16 + l16;
#pragma unroll
      for (int r = 0; r < 4; ++r)
        Ts[cl * 72 + (w * 16 + quad * 4 + r)] = f2b(acc[c][r]);
    }
    __syncthreads();
    int nl = t >> 2, ch = t & 3;
    uint4 v0 = *(const uint4*)(&Ts[nl * 72 + ch * 16]);
    uint4 v1 = *(const uint4*)(&Ts[nl * 72 + ch * 16 + 8]);
    ushort* dst = W2T + (size_t)(n0 + nl) * DMODEL + m0 + ch * 16;
    *(uint4*)dst = v0;
    *(uint4*)(dst + 8) = v1;
  }
}

// ---------------- K2a: qb[b,j] = sum_d qs[b,d] * wq[d,j] ----------------
__global__ __launch_bounds__(256) void qbar_k(
    const float* __restrict__ P, const void* __restrict__ wq,
    float* __restrict__ qb) {
  __shared__ float qs[DMODEL];
  __shared__ float red[4][64];
  int bf = detect_bf16(wq);
  int b = blockIdx.x >> 3, g = blockIdx.x & 7;
  int t = threadIdx.x;
  for (int d = t; d < DMODEL; d += 256) {
    float a = 0.f;
#pragma unroll
    for (int c = 0; c < 64; ++c) a += P[(size_t)(b * 64 + c) * DMODEL + d];
    qs[d] = a;
  }
  __syncthreads();
  int part = t >> 6, jl = t & 63;
  int j = g * 64 + jl;
  float acc = 0.f;
  int d0 = part * 128;
#pragma unroll 8
  for (int d = d0; d < d0 + 128; ++d)
    acc += qs[d] * ld1(wq, (size_t)d * DMODEL + j, bf);
  red[part][jl] = acc;
  __syncthreads();
  if (part == 0)
    qb[(size_t)b * DMODEL + j] = red[0][jl] + red[1][jl] + red[2][jl] + red[3][jl];
}

// ---------------- K2b: u[b,t] = wk[t,:] . qb[b,:] ----------------
__global__ __launch_bounds__(256) void u_k(
    const float* __restrict__ qb, const void* __restrict__ wk,
    float* __restrict__ u, const void* __restrict__ probe) {
  int bf = detect_bf16(probe);
  int gw = (blockIdx.x * 256 + threadIdx.x) >> 6;
  int lane = threadIdx.x & 63;
  int b = gw >> 9, t = gw & 511;
  float kv[8];
  ld8v(wk, (size_t)t * DMODEL + lane * 8, bf, kv);
  const float* qbb = qb + (size_t)b * DMODEL + lane * 8;
  float acc = 0.f;
#pragma unroll
  for (int i = 0; i < 8; ++i) acc += kv[i] * qbb[i];
#pragma unroll
  for (int off = 32; off > 0; off >>= 1) acc += __shfl_down(acc, off);
  if (lane == 0) u[(size_t)b * DMODEL + t] = acc;
}

// ---------------- K3: mean_corr[b,j] = (keys[b,j,:] . u[b,:]) / (H*L) -------
__global__ __launch_bounds__(256) void mean_corr_k(
    const void* __restrict__ keys, const float* __restrict__ u,
    float* __restrict__ mc, const void* __restrict__ probe) {
  int bf = detect_bf16(probe);
  int wid = (blockIdx.x * 256 + threadIdx.x) >> 6;
  int lane = threadIdx.x & 63;
  int b = wid >> 11, j = wid & (LEN - 1);
  float kv[8];
  ld8v(keys, (((size_t)b * LEN + j) << 9) + lane * 8, bf, kv);
  const float* ub = u + (size_t)b * DMODEL + lane * 8;
  float acc = 0.f;
#pragma unroll
  for (int i = 0; i < 8; ++i) acc += kv[i] * ub[i];
#pragma unroll
  for (int off = 32; off > 0; off >>= 1) acc += __shfl_down(acc, off);
  if (lane == 0) mc[(size_t)b * LEN + j] = acc * (1.f / 16384.f);
}

// ---------------- K4: top-7 + softmax per batch ----------------
__global__ void topk_softmax(const float* __restrict__ mc,
                             float* __restrict__ wts, int* __restrict__ dls) {
  __shared__ float vals[LEN];
  __shared__ float rv[4];
  __shared__ int ri[4];
  __shared__ float bv_s[TOPK];
  __shared__ int bi_s[TOPK];
  int b = blockIdx.x, t = threadIdx.x;
  for (int i = t; i < LEN; i += 256) vals[i] = mc[(size_t)b * LEN + i];
  __syncthreads();
  for (int it = 0; it < TOPK; ++it) {
    float bv = -3.0e38f; int bi = 0;
#pragma unroll
    for (int c = 0; c < LEN / 256; ++c) {
      int i = t + c * 256;
      float v = vals[i];
      if (v > bv) { bv = v; bi = i; }
    }
#pragma unroll
    for (int off = 32; off > 0; off >>= 1) {
      float ov = __shfl_down(bv, off);
      int   oi = __shfl_down(bi, off);
      if (ov > bv || (ov == bv && oi < bi)) { bv = ov; bi = oi; }
    }
    if ((t & 63) == 0) { rv[t >> 6] = bv; ri[t >> 6] = bi; }
    __syncthreads();
    if (t == 0) {
      float fv = rv[0]; int fi = ri[0];
      for (int w = 1; w < 4; ++w)
        if (rv[w] > fv || (rv[w] == fv && ri[w] < fi)) { fv = rv[w]; fi = ri[w]; }
      bv_s[it] = fv; bi_s[it] = fi;
      vals[fi] = -3.0e38f;
    }
    __syncthreads();
  }
  if (t == 0) {
    float m = bv_s[0];
    float e[TOPK], s = 0.f;
#pragma unroll
    for (int i = 0; i < TOPK; ++i) { e[i] = __expf(bv_s[i] - m); s += e[i]; }
    float inv = 1.f / s;
#pragma unroll
    for (int i = 0; i < TOPK; ++i) {
      wts[b * 8 + i] = e[i] * inv;
      dls[b * 8 + i] = bi_s[i];
    }
  }
}

// ---------------- K5: Amix[row][d] = sum_k w_k * VB[b,(l+d_k)%L,d] (bf16 in) -
__global__ __launch_bounds__(256) void mix_k(
    const ushort* __restrict__ VB, const float* __restrict__ wts,
    const int* __restrict__ dls, ushort* __restrict__ Amix) {
  int t = threadIdx.x;
  int row = blockIdx.x * 4 + (t >> 6);
  int lane = t & 63;
  int b = row >> 11, l = row & (LEN - 1);
  float w[TOPK]; int dl[TOPK];
#pragma unroll
  for (int i = 0; i < TOPK; ++i) { w[i] = wts[b * 8 + i]; dl[i] = dls[b * 8 + i]; }
  float acc[8] = {0,0,0,0,0,0,0,0};
#pragma unroll
  for (int i = 0; i < TOPK; ++i) {
    int src = (l + dl[i]) & (LEN - 1);
    uint4 v = *(const uint4*)(VB + (((size_t)b * LEN + src) << 9) + lane * 8);
    const ushort* vs = (const ushort*)&v;
#pragma unroll
    for (int j = 0; j < 8; ++j) acc[j] += w[i] * b2f(vs[j]);
  }
  union { ushort o[8]; uint4 v; } pk;
#pragma unroll
  for (int j = 0; j < 8; ++j) pk.o[j] = f2b(acc[j]);
  *(uint4*)(Amix + ((size_t)row << 9) + lane * 8) = pk.v;
}

// ---------------- K6: out[8192,512] = Amix @ W2T^T (128x128 tile) ----------
__global__ __launch_bounds__(256) void gemm_out(
    const ushort* __restrict__ Amix, const ushort* __restrict__ W2T,
    void* __restrict__ out, const void* __restrict__ probe) {
  __shared__ ushort As[128 * LDK];
  __shared__ ushort Bs[128 * LDK];
  int bf = detect_bf16(probe);
  int t = threadIdx.x;
  int n0 = blockIdx.x * 128, m0 = blockIdx.y * 128;
  int w = t >> 6, lane = t & 63;
  int quad = lane >> 4, l16 = lane & 15;
  int wr = (w & 1) * 64, wc = (w >> 1) * 64;
  floatx4 acc[4][4];
#pragma unroll
  for (int r = 0; r < 4; ++r)
#pragma unroll
    for (int c = 0; c < 4; ++c) acc[r][c] = (floatx4){0, 0, 0, 0};
  int sr = t >> 2, sc = (t & 3) * 8;

  for (int k0 = 0; k0 < DMODEL; k0 += 32) {
    *(uint4*)(&As[sr * LDK + sc])        = *(const uint4*)(Amix + (size_t)(m0 + sr) * DMODEL + k0 + sc);
    *(uint4*)(&As[(sr + 64) * LDK + sc]) = *(const uint4*)(Amix + (size_t)(m0 + sr + 64) * DMODEL + k0 + sc);
    *(uint4*)(&Bs[sr * LDK + sc])        = *(const uint4*)(W2T + (size_t)(n0 + sr) * DMODEL + k0 + sc);
    *(uint4*)(&Bs[(sr + 64) * LDK + sc]) = *(const uint4*)(W2T + (size_t)(n0 + sr + 64) * DMODEL + k0 + sc);
    __syncthreads();
    short8 af[4], bfg[4];
#pragma unroll
    for (int r = 0; r < 4; ++r)
      af[r] = *(const short8*)(&As[(wr + r * 16 + l16) * LDK + quad * 8]);
#pragma unroll
    for (int c = 0; c < 4; ++c)
      bfg[c] = *(const short8*)(&Bs[(wc + c * 16 + l16) * LDK + quad * 8]);
#pragma unroll
    for (int r = 0; r < 4; ++r)
#pragma unroll
      for (int c = 0; c < 4; ++c)
        acc[r][c] = __builtin_amdgcn_mfma_f32_16x16x32_bf16(af[r], bfg[c], acc[r][c], 0, 0, 0);
    __syncthreads();
  }
#pragma unroll
  for (int r = 0; r < 4; ++r) {
    int row = m0 + wr + r * 16 + quad * 4;
#pragma unroll
    for (int c = 0; c < 4; ++c) {
      int col = n0 + wc + c * 16 + l16;
#pragma unroll
      for (int rr = 0; rr < 4; ++rr) {
        size_t oidx = (size_t)(row + rr) * DMODEL + col;
        float v = acc[r][c][rr];
        if (bf) ((ushort*)out)[oidx] = f2b(v);
        else    ((float*)out)[oidx] = v;
      }
    }
  }
}

extern "C" void kernel_launch(void* const* d_in, const int* in_sizes, int n_in,
                              void* d_out, int out_size, void* d_ws, size_t ws_size,
                              hipStream_t stream) {
  const void* queries = d_in[0];
  const void* keys    = d_in[1];
  const void* values  = d_in[2];
  const void* wq      = d_in[3];
  const void* wk      = d_in[4];
  const void* wv      = d_in[5];
  const void* wo      = d_in[6];

  char* ws = (char*)d_ws;
  float*  P    = (float*)(ws + 0);           // 256*512*4 = 512 KB
  ushort* W2T  = (ushort*)(ws + 524288);     // 512*512*2 = 512 KB
  float*  QB   = (float*)(ws + 1048576);     // 8 KB
  float*  U    = (float*)(ws + 1056768);     // 8 KB
  float*  MC   = (float*)(ws + 1064960);     // 32 KB
  float*  WT   = (float*)(ws + 1097728);     // 128 B
  int*    DL   = (int*)  (ws + 1097856);     // 128 B
  ushort* VB   = (ushort*)(ws + 2097152);    // 8192*512*2 = 8 MB
  ushort* AMIX = (ushort*)(ws + 10485760);   // 8 MB; total 18 MB

  prep_k<<<2368, 256, 0, stream>>>(queries, values, wv, wo, wq, P, VB, W2T);
  qbar_k<<<NBATCH * 8, 256, 0, stream>>>(P, wq, QB);
  u_k<<<NBATCH * 512 / 4, 256, 0, stream>>>(QB, wk, U, wq);
  mean_corr_k<<<NBATCH * LEN / 4, 256, 0, stream>>>(keys, U, MC, wq);
  topk_softmax<<<NBATCH, 256, 0, stream>>>(MC, WT, DL);
  mix_k<<<NBATCH * LEN / 4, 256, 0, stream>>>(VB, WT, DL, AMIX);
  gemm_out<<<dim3(4, 64), 256, 0, stream>>>(AMIX, W2T, d_out, wq);
}